// Round 5
// baseline (201.388 us; speedup 1.0000x reference)
//
#include <hip/hip_runtime.h>
#include <stdint.h>

#define HH 224
#define WW 224
#define BB 4
#define PP 7          // seams per direction
#define SEG 28
#define BW 5
#define MM 11         // 2*BW+1

#define POS_INF_I 0x7F800000

typedef const __attribute__((address_space(1))) unsigned int* gas_ptr;
typedef __attribute__((address_space(3))) unsigned int* las_ptr;

// map-compose for 11-entry 4-bit-nibble maps packed in u64:  H[i] = F[G[i]]
__device__ inline unsigned long long mcompose(unsigned long long F, unsigned long long G) {
    unsigned long long H = 0ull;
#pragma unroll
    for (int i = 0; i < 11; ++i) {
        unsigned g = (unsigned)(G >> (4 * i)) & 15u;
        H |= ((F >> (4 * g)) & 15ull) << (4 * i);
    }
    return H;
}

// ---------------------------------------------------------------------------
// DP kernel (unchanged from R4 — verified, absmax 0)
// ---------------------------------------------------------------------------
__global__ __launch_bounds__(64) void dp_kernel(const float* __restrict__ grad,
                                                int* __restrict__ coords_v,
                                                int* __restrict__ coords_h) {
    __shared__ __align__(16) float gseg[225 * 16];

    const int tid = threadIdx.x;
    const int l   = tid & 15;
    const int sid = blockIdx.x;
    const int p   = sid % PP;
    const int dir = (sid / PP) & 1;
    const int b   = sid / (2 * PP);
    const int base = SEG * (p + 1);
    const float* gb = grad + b * (HH * WW);

    {
        const int r  = tid >> 4;
        const int m  = tid & 15;
        const int sS = (dir == 0) ? WW : 1;
        const int sM = (dir == 0) ? 1  : WW;
        const float* src = gb + r * sS + (base - BW + m) * sM;
        const long stepBytes = (long)(4 * sS) * 4;
#pragma unroll 8
        for (int c = 0; c < 56; ++c) {
            __builtin_amdgcn_global_load_lds((gas_ptr)(const void*)src,
                                             (las_ptr)(void*)(&gseg[c * 64]), 4, 0, 0);
            src = (const float*)((const char*)src + stepBytes);
        }
    }
    __syncthreads();

    const float lane_add = (l < MM) ? 0.0f : __int_as_float(POS_INF_I);
    const float* gp = &gseg[l];

    unsigned wreg[16] = {};

#define DP_STEP(gval, ownb, jj_c)                                                       \
    {                                                                                   \
        float v1 = cost;                                                                \
        float v0 = __int_as_float(__builtin_amdgcn_update_dpp(                          \
            POS_INF_I, __float_as_int(cost), 0x111, 0xf, 0xf, false));                  \
        float v2 = __int_as_float(__builtin_amdgcn_update_dpp(                          \
            POS_INF_I, __float_as_int(cost), 0x101, 0xf, 0xf, false));                  \
        bool a01 = (v0 <= v1), a02 = (v0 <= v2), a12 = (v1 <= v2);                      \
        bool aa  = a01 && a02;                                                          \
        unsigned long long A   = __ballot(aa);                                          \
        unsigned long long C12 = __ballot(a12);                                         \
        unsigned long long B0 = ~A & C12;                                               \
        unsigned long long B1 = ~A & ~C12;                                              \
        float mv = aa ? v0 : (a12 ? v1 : v2);                                           \
        cost = mv - (gval) + lane_add;                                                  \
        unsigned wv = (unsigned)(B0 & 0x7FFull) | ((unsigned)(B1 & 0x7FFull) << 11);    \
        wreg[(jj_c)] = (ownb) ? wv : wreg[(jj_c)];                                      \
    }

    float cost = -gp[0] + lane_add;
    float buf[16], c0[16];
#pragma unroll
    for (int k = 0; k < 16; ++k) buf[k] = gp[(1 + k) * 16];
    for (int t = 0; t < 13; ++t) {
        const bool own = (tid == t);
#pragma unroll
        for (int k = 0; k < 16; ++k) c0[k] = buf[k];
#pragma unroll
        for (int k = 0; k < 16; ++k) buf[k] = gp[(16 * (t + 1) + 1 + k) * 16];
#pragma unroll
        for (int k = 0; k < 16; ++k) DP_STEP(c0[k], own, k)
    }
    {
        const bool own = (tid == 13);
#pragma unroll
        for (int k = 0; k < 15; ++k) DP_STEP(buf[k], own, k)
    }
#undef DP_STEP

    float bc = cost;
    int   bi = l;
#pragma unroll
    for (int mask = 1; mask < 16; mask <<= 1) {
        float oc = __shfl_xor(bc, mask, 16);
        int   oi = __shfl_xor(bi, mask, 16);
        if (oc < bc || (oc == bc && oi < bi)) { bc = oc; bi = oi; }
    }
    const int idx_last = bi;

    const int mcnt = (l < 13) ? 16 : ((l == 13) ? 15 : 0);
    const unsigned long long IDMAP = 0xA9876543210ull;
    unsigned long long L = IDMAP;
#pragma unroll
    for (int jj = 15; jj >= 0; --jj) {
        if (jj < mcnt) {
            unsigned ww = wreg[jj];
            unsigned long long M = 0ull;
#pragma unroll
            for (int i = 0; i < MM; ++i) {
                unsigned sel = ((ww >> i) & 1u) + 2u * ((ww >> (11 + i)) & 1u);
                M |= ((unsigned long long)(i + (int)sel - 1)) << (4 * i);
            }
            L = mcompose(M, L);
        }
    }
    unsigned long long I = L;
#pragma unroll
    for (int d = 1; d < 16; d <<= 1) {
        unsigned long long O = __shfl_down(I, d, 16);
        if (l + d < 16) I = mcompose(I, O);
    }
    unsigned long long R = __shfl_down(I, 1, 16);
    if (l == 15) R = IDMAP;

    int* cout = (dir == 0) ? coords_v : coords_h;
    if (tid == 15) cout[(b * HH + 223) * PP + p] = base + idx_last - BW;
    if (tid < 16) {
        unsigned v = (unsigned)(R >> (4 * idx_last)) & 15u;
#pragma unroll
        for (int jj = 15; jj >= 0; --jj) {
            if (jj < mcnt) {
                unsigned ww = wreg[jj];
                unsigned sel = ((ww >> v) & 1u) + 2u * ((ww >> (11 + v)) & 1u);
                v = v + sel - 1u;
                cout[(b * HH + (16 * l + jj)) * PP + p] = base + (int)v - BW;
            }
        }
    }
}

// ---------------------------------------------------------------------------
// Fused kernel: initial labels + all 5 vote iterations in LDS (halo replication).
// Tile 28x28 out, halo 15 -> 58x58 region. Grid 8x8x4 = 256 blocks x 256 thr.
// ---------------------------------------------------------------------------
#define TS   28
#define RG   58          // 28 + 2*15
#define LST  64          // LDS row stride (bytes)

__global__ __launch_bounds__(256) void seg_vote_kernel(const int* __restrict__ cv,
                                                       const int* __restrict__ ch,
                                                       int* __restrict__ out) {
    __shared__ __align__(8) unsigned char labA[RG * LST];   // 3712 B
    __shared__ __align__(8) unsigned char labB[RG * LST];
    __shared__ unsigned bins[16 * 256];                     // byte-packed 64 bins / thread

    const int t  = threadIdx.x;
    const int b  = blockIdx.z;
    const int GX0 = blockIdx.x * TS - 15;
    const int GY0 = blockIdx.y * TS - 15;

    // ---- stage 0: initial labels into labA for all in-image region px ----
    for (int idx = t; idx < RG * RG; idx += 256) {
        int ly = idx / RG, lx = idx - ly * RG;
        int gy = GY0 + ly, gx = GX0 + lx;
        if ((unsigned)gy < HH && (unsigned)gx < WW) {
            const int* cvp = cv + (b * HH + gy) * PP;
            const int* chp = ch + (b * WW + gx) * PP;
            int v = 0, h = 0;
#pragma unroll
            for (int q = 0; q < PP; ++q) { v += (cvp[q] <= gx); h += (chp[q] <= gy); }
            labA[ly * LST + lx] = (unsigned char)(v + 8 * h);
        }
    }
    __syncthreads();

    const int sizes[5] = {52, 46, 40, 34, 28};

    for (int r = 1; r <= 5; ++r) {
        const unsigned char* src = (r & 1) ? labA : labB;
        unsigned char*       dst = (r & 1) ? labB : labA;
        const unsigned* src32 = (const unsigned*)src;
        const int size = sizes[r - 1];
        const int off  = 3 * r;
        const int npx  = size * size;

        for (int idx = t; idx < npx; idx += 256) {
            int j = idx / size, i = idx - j * size;
            int ly = off + j, lx = off + i;
            int gy = GY0 + ly, gx = GX0 + lx;
            if ((unsigned)gy >= HH || (unsigned)gx >= WW) continue;

            // gather 7 rows of 7 bytes each via 3 aligned dword reads + funnel
            unsigned long long rows[7];
#pragma unroll
            for (int dy = -3; dy <= 3; ++dy) {
                int o  = (ly + dy) * LST + lx - 3;
                int a  = o >> 2;
                int sh = (o & 3) * 8;
                unsigned b0 = src32[a], b1 = src32[a + 1], b2 = src32[a + 2];
                unsigned long long lo = ((unsigned long long)b1 << 32) | b0;
                unsigned long long row = lo >> sh;
                if (sh) row |= (unsigned long long)b2 << (64 - sh);
                rows[dy + 3] = row & 0x00FFFFFFFFFFFFFFull;
            }

            const unsigned lab_c = src[ly * LST + lx];

            // uniform fast path: all 49 bytes (incl. any garbage) == lab_c
            unsigned long long rep = (unsigned long long)lab_c * 0x0001010101010101ull;
            bool uni = true;
#pragma unroll
            for (int k = 0; k < 7; ++k) uni = uni && (rows[k] == rep);

            int best_k;
            if (uni) {
                best_k = (int)lab_c;
            } else {
#pragma unroll
                for (int c = 0; c < 16; ++c) bins[c * 256 + t] = 0u;
#pragma unroll
                for (int dy = -3; dy <= 3; ++dy) {
                    if ((unsigned)(gy + dy) >= HH) continue;
                    unsigned long long row = rows[dy + 3];
                    const int ay = dy < 0 ? -dy : dy;
#pragma unroll
                    for (int dx = -3; dx <= 3; ++dx) {
                        if ((unsigned)(gx + dx) >= WW) continue;
                        int lab = (int)((row >> (8 * (dx + 3))) & 255u);
                        const int ax = dx < 0 ? -dx : dx;
                        const int d = ay > ax ? ay : ax;
                        const unsigned wgt = (d <= 1) ? 3u : (unsigned)(4 - d);
                        atomicAdd(&bins[(lab >> 2) * 256 + t], wgt << ((lab & 3) * 8));
                    }
                }
                int best_s = 0; best_k = 0;
#pragma unroll
                for (int c = 0; c < 16; ++c) {
                    unsigned wd = bins[c * 256 + t];
                    if (wd) {
#pragma unroll
                        for (int q = 0; q < 4; ++q) {
                            int s = (int)((wd >> (q * 8)) & 255u);
                            if (s > best_s) { best_s = s; best_k = c * 4 + q; }
                        }
                    }
                }
            }

            if (r < 5) dst[ly * LST + lx] = (unsigned char)best_k;
            else       out[(b * HH + gy) * WW + gx] = best_k;
        }
        __syncthreads();
    }
}

// ---------------------------------------------------------------------------
extern "C" void kernel_launch(void* const* d_in, const int* in_sizes, int n_in,
                              void* d_out, int out_size, void* d_ws, size_t ws_size,
                              hipStream_t stream) {
    const float* grad = (const float*)d_in[0];
    int* out = (int*)d_out;
    char* ws = (char*)d_ws;

    int* cv = (int*)(ws);             // 25088 B
    int* ch = (int*)(ws + 25088);     // 25088 B

    dp_kernel<<<56, 64, 0, stream>>>(grad, cv, ch);

    dim3 grid(WW / TS, HH / TS, BB), blk(256, 1, 1);
    seg_vote_kernel<<<grid, blk, 0, stream>>>(cv, ch, out);
}

// Round 6
// 140.440 us; speedup vs baseline: 1.4340x; 1.4340x over previous
//
#include <hip/hip_runtime.h>
#include <stdint.h>

#define HH 224
#define WW 224
#define BB 4
#define PP 7          // seams per direction
#define SEG 28
#define BW 5
#define MM 11         // 2*BW+1

#define POS_INF_I 0x7F800000

typedef const __attribute__((address_space(1))) unsigned int* gas_ptr;
typedef __attribute__((address_space(3))) unsigned int* las_ptr;

// map-compose for 11-entry 4-bit-nibble maps packed in u64:  H[i] = F[G[i]]
__device__ inline unsigned long long mcompose(unsigned long long F, unsigned long long G) {
    unsigned long long H = 0ull;
#pragma unroll
    for (int i = 0; i < 11; ++i) {
        unsigned g = (unsigned)(G >> (4 * i)) & 15u;
        H |= ((F >> (4 * g)) & 15ull) << (4 * i);
    }
    return H;
}

// ---------------------------------------------------------------------------
// DP kernel (unchanged from R4 — verified, absmax 0)
// ---------------------------------------------------------------------------
__global__ __launch_bounds__(64) void dp_kernel(const float* __restrict__ grad,
                                                int* __restrict__ coords_v,
                                                int* __restrict__ coords_h) {
    __shared__ __align__(16) float gseg[225 * 16];

    const int tid = threadIdx.x;
    const int l   = tid & 15;
    const int sid = blockIdx.x;
    const int p   = sid % PP;
    const int dir = (sid / PP) & 1;
    const int b   = sid / (2 * PP);
    const int base = SEG * (p + 1);
    const float* gb = grad + b * (HH * WW);

    {
        const int r  = tid >> 4;
        const int m  = tid & 15;
        const int sS = (dir == 0) ? WW : 1;
        const int sM = (dir == 0) ? 1  : WW;
        const float* src = gb + r * sS + (base - BW + m) * sM;
        const long stepBytes = (long)(4 * sS) * 4;
#pragma unroll 8
        for (int c = 0; c < 56; ++c) {
            __builtin_amdgcn_global_load_lds((gas_ptr)(const void*)src,
                                             (las_ptr)(void*)(&gseg[c * 64]), 4, 0, 0);
            src = (const float*)((const char*)src + stepBytes);
        }
    }
    __syncthreads();

    const float lane_add = (l < MM) ? 0.0f : __int_as_float(POS_INF_I);
    const float* gp = &gseg[l];

    unsigned wreg[16] = {};

#define DP_STEP(gval, ownb, jj_c)                                                       \
    {                                                                                   \
        float v1 = cost;                                                                \
        float v0 = __int_as_float(__builtin_amdgcn_update_dpp(                          \
            POS_INF_I, __float_as_int(cost), 0x111, 0xf, 0xf, false));                  \
        float v2 = __int_as_float(__builtin_amdgcn_update_dpp(                          \
            POS_INF_I, __float_as_int(cost), 0x101, 0xf, 0xf, false));                  \
        bool a01 = (v0 <= v1), a02 = (v0 <= v2), a12 = (v1 <= v2);                      \
        bool aa  = a01 && a02;                                                          \
        unsigned long long A   = __ballot(aa);                                          \
        unsigned long long C12 = __ballot(a12);                                         \
        unsigned long long B0 = ~A & C12;                                               \
        unsigned long long B1 = ~A & ~C12;                                              \
        float mv = aa ? v0 : (a12 ? v1 : v2);                                           \
        cost = mv - (gval) + lane_add;                                                  \
        unsigned wv = (unsigned)(B0 & 0x7FFull) | ((unsigned)(B1 & 0x7FFull) << 11);    \
        wreg[(jj_c)] = (ownb) ? wv : wreg[(jj_c)];                                      \
    }

    float cost = -gp[0] + lane_add;
    float buf[16], c0[16];
#pragma unroll
    for (int k = 0; k < 16; ++k) buf[k] = gp[(1 + k) * 16];
    for (int t = 0; t < 13; ++t) {
        const bool own = (tid == t);
#pragma unroll
        for (int k = 0; k < 16; ++k) c0[k] = buf[k];
#pragma unroll
        for (int k = 0; k < 16; ++k) buf[k] = gp[(16 * (t + 1) + 1 + k) * 16];
#pragma unroll
        for (int k = 0; k < 16; ++k) DP_STEP(c0[k], own, k)
    }
    {
        const bool own = (tid == 13);
#pragma unroll
        for (int k = 0; k < 15; ++k) DP_STEP(buf[k], own, k)
    }
#undef DP_STEP

    float bc = cost;
    int   bi = l;
#pragma unroll
    for (int mask = 1; mask < 16; mask <<= 1) {
        float oc = __shfl_xor(bc, mask, 16);
        int   oi = __shfl_xor(bi, mask, 16);
        if (oc < bc || (oc == bc && oi < bi)) { bc = oc; bi = oi; }
    }
    const int idx_last = bi;

    const int mcnt = (l < 13) ? 16 : ((l == 13) ? 15 : 0);
    const unsigned long long IDMAP = 0xA9876543210ull;
    unsigned long long L = IDMAP;
#pragma unroll
    for (int jj = 15; jj >= 0; --jj) {
        if (jj < mcnt) {
            unsigned ww = wreg[jj];
            unsigned long long M = 0ull;
#pragma unroll
            for (int i = 0; i < MM; ++i) {
                unsigned sel = ((ww >> i) & 1u) + 2u * ((ww >> (11 + i)) & 1u);
                M |= ((unsigned long long)(i + (int)sel - 1)) << (4 * i);
            }
            L = mcompose(M, L);
        }
    }
    unsigned long long I = L;
#pragma unroll
    for (int d = 1; d < 16; d <<= 1) {
        unsigned long long O = __shfl_down(I, d, 16);
        if (l + d < 16) I = mcompose(I, O);
    }
    unsigned long long R = __shfl_down(I, 1, 16);
    if (l == 15) R = IDMAP;

    int* cout = (dir == 0) ? coords_v : coords_h;
    if (tid == 15) cout[(b * HH + 223) * PP + p] = base + idx_last - BW;
    if (tid < 16) {
        unsigned v = (unsigned)(R >> (4 * idx_last)) & 15u;
#pragma unroll
        for (int jj = 15; jj >= 0; --jj) {
            if (jj < mcnt) {
                unsigned ww = wreg[jj];
                unsigned sel = ((ww >> v) & 1u) + 2u * ((ww >> (11 + v)) & 1u);
                v = v + sel - 1u;
                cout[(b * HH + (16 * l + jj)) * PP + p] = base + (int)v - BW;
            }
        }
    }
}

// ---------------------------------------------------------------------------
// Shared histogram helpers (proven logic from R4's vote_kernel)
// ---------------------------------------------------------------------------
#define RW 38          // region width  (tile 32 + 2*3)
#define RH 14          // region height (tile 8  + 2*3)
#define RSTR 40        // LDS region row stride

__device__ inline void hist_zero(unsigned* bins, int t) {
#pragma unroll
    for (int c = 0; c < 16; ++c) bins[c * 256 + t] = 0u;
}
__device__ inline void hist_add(unsigned* bins, int t, int lab, unsigned wgt) {
    atomicAdd(&bins[(lab >> 2) * 256 + t], wgt << ((lab & 3) * 8));
}
__device__ inline int hist_argmax(const unsigned* bins, int t) {
    int best_s = 0, best_k = 0;
#pragma unroll
    for (int c = 0; c < 16; ++c) {
        unsigned wd = bins[c * 256 + t];
        if (wd) {
#pragma unroll
            for (int q = 0; q < 4; ++q) {
                int s = (int)((wd >> (q * 8)) & 255u);
                if (s > best_s) { best_s = s; best_k = c * 4 + q; }
            }
        }
    }
    return best_k;
}
__device__ inline unsigned cheb_w(int dy, int dx) {
    int ay = dy < 0 ? -dy : dy, ax = dx < 0 ? -dx : dx;
    int d = ay > ax ? ay : ax;
    return (d <= 1) ? 3u : (unsigned)(4 - d);
}

// ---------------------------------------------------------------------------
// Fused initial-label + vote1. Grid (7,28,4) x (32,8).
// ---------------------------------------------------------------------------
__global__ __launch_bounds__(256) void labvote_kernel(const int* __restrict__ cv,
                                                      const int* __restrict__ ch,
                                                      unsigned char* __restrict__ out8) {
    __shared__ unsigned char lab[RH * RSTR];
    __shared__ unsigned bins[16 * 256];
    const int tx = threadIdx.x, ty = threadIdx.y;
    const int t  = ty * 32 + tx;
    const int b  = blockIdx.z;
    const int GX0 = blockIdx.x * 32, GY0 = blockIdx.y * 8;

    // stage: analytic initial labels for the 38x14 halo region
    for (int idx = t; idx < RW * RH; idx += 256) {
        int j = idx / RW, i = idx - j * RW;
        int gx = GX0 - 3 + i, gy = GY0 - 3 + j;
        if ((unsigned)gx < WW && (unsigned)gy < HH) {
            const int* cvp = cv + (b * HH + gy) * PP;
            const int* chp = ch + (b * WW + gx) * PP;
            int v = 0, h = 0;
#pragma unroll
            for (int q = 0; q < PP; ++q) { v += (cvp[q] <= gx); h += (chp[q] <= gy); }
            lab[j * RSTR + i] = (unsigned char)(v + 8 * h);
        }
    }
    __syncthreads();

    const int gx = GX0 + tx, gy = GY0 + ty;
    hist_zero(bins, t);
#pragma unroll
    for (int dy = -3; dy <= 3; ++dy) {
        if ((unsigned)(gy + dy) >= HH) continue;
#pragma unroll
        for (int dx = -3; dx <= 3; ++dx) {
            if ((unsigned)(gx + dx) >= WW) continue;
            int lb = lab[(ty + 3 + dy) * RSTR + (tx + 3 + dx)];
            hist_add(bins, t, lb, cheb_w(dy, dx));
        }
    }
    out8[(b * HH + gy) * WW + gx] = (unsigned char)hist_argmax(bins, t);
}

// ---------------------------------------------------------------------------
// Fused vote pair: iter A reads from GLOBAL (halo-free) for the 38x14
// intermediate region -> LDS; iter B votes from LDS -> out (u8 or i32).
// Grid (7,28,4) x (32,8).
// ---------------------------------------------------------------------------
__global__ __launch_bounds__(256) void votepair_kernel(const unsigned char* __restrict__ in,
                                                       unsigned char* __restrict__ out8,
                                                       int* __restrict__ out32) {
    __shared__ unsigned char mid[RH * RSTR];
    __shared__ unsigned bins[16 * 256];
    const int tx = threadIdx.x, ty = threadIdx.y;
    const int t  = ty * 32 + tx;
    const int b  = blockIdx.z;
    const int GX0 = blockIdx.x * 32, GY0 = blockIdx.y * 8;
    const unsigned char* img = in + b * (HH * WW);

    // iter A: intermediate labels for region px (global-input histogram)
    for (int idx = t; idx < RW * RH; idx += 256) {
        int j = idx / RW, i = idx - j * RW;
        int gx = GX0 - 3 + i, gy = GY0 - 3 + j;
        if ((unsigned)gx < WW && (unsigned)gy < HH) {
            hist_zero(bins, t);
#pragma unroll
            for (int dy = -3; dy <= 3; ++dy) {
                if ((unsigned)(gy + dy) >= HH) continue;
#pragma unroll
                for (int dx = -3; dx <= 3; ++dx) {
                    if ((unsigned)(gx + dx) >= WW) continue;
                    int lb = img[(gy + dy) * WW + (gx + dx)];
                    hist_add(bins, t, lb, cheb_w(dy, dx));
                }
            }
            mid[j * RSTR + i] = (unsigned char)hist_argmax(bins, t);
        }
    }
    __syncthreads();

    // iter B: own pixel from LDS intermediates
    const int gx = GX0 + tx, gy = GY0 + ty;
    hist_zero(bins, t);
#pragma unroll
    for (int dy = -3; dy <= 3; ++dy) {
        if ((unsigned)(gy + dy) >= HH) continue;
#pragma unroll
        for (int dx = -3; dx <= 3; ++dx) {
            if ((unsigned)(gx + dx) >= WW) continue;
            int lb = mid[(ty + 3 + dy) * RSTR + (tx + 3 + dx)];
            hist_add(bins, t, lb, cheb_w(dy, dx));
        }
    }
    int best_k = hist_argmax(bins, t);
    int o = (b * HH + gy) * WW + gx;
    if (out8)  out8[o]  = (unsigned char)best_k;
    if (out32) out32[o] = best_k;
}

// ---------------------------------------------------------------------------
extern "C" void kernel_launch(void* const* d_in, const int* in_sizes, int n_in,
                              void* d_out, int out_size, void* d_ws, size_t ws_size,
                              hipStream_t stream) {
    const float* grad = (const float*)d_in[0];
    int* out = (int*)d_out;
    char* ws = (char*)d_ws;

    int* cv = (int*)(ws);                               // 25088 B
    int* ch = (int*)(ws + 25088);                       // 25088 B
    unsigned char* laW = (unsigned char*)(ws + 50176);  // u8 label buffer (ws)
    unsigned char* laD = (unsigned char*)d_out;         // u8 buffer inside d_out (overwritten at end)

    dp_kernel<<<56, 64, 0, stream>>>(grad, cv, ch);

    dim3 grid(WW / 32, HH / 8, BB), blk(32, 8, 1);
    labvote_kernel<<<grid, blk, 0, stream>>>(cv, ch, laD);                 // v1 -> laD
    votepair_kernel<<<grid, blk, 0, stream>>>(laD, laW, nullptr);          // v2,v3 -> laW
    votepair_kernel<<<grid, blk, 0, stream>>>(laW, nullptr, out);          // v4,v5 -> int out
}